// Round 17
// baseline (372.526 us; speedup 1.0000x reference)
//
#include <hip/hip_runtime.h>
#include <hip/hip_bf16.h>
#include <math.h>

#define NPTS   32768

// Workspace float offsets
#define CONV_OFF0 0         // conv outputs bf16 channels-last
#define CONV_OFF1 983040
#define CONV_OFF2 1228800
#define CONV_OFF3 1290240
#define F_RY     1312256   // float[4][48]
#define F_RX     1312448   // float[4][160]
#define F_POOLED 1313088   // float[2][256]  (zeroed; conv atomics)
#define F_GSUM   1313600   // float[16][256] (zeroed; 16-way striped gather atomics)
#define F_CNT    1317696   // uint[2]        (zeroed; last-block counters)
#define F_LWS    1317704   // float[2][4]    (written by conv lw-fold)
#define F_GATES  1317712   // float[2][128]  (written by gather se-fold)
#define F_PTPART 1317968   // float[64][4]   (fully written by prep blocks)
#define F_INBF   1318272   // bf16 channels-last inputs: 5,222,400 bf16 ele
#define INBF_ELE 5222400
#define F_WPACK  (F_INBF + INBF_ELE/2)    // bf16 packed lat weights
#define F_IMGTBF (F_WPACK + 294912)       // bf16 imgt_w -> ends ~16.96 MB

typedef short bf16x8 __attribute__((ext_vector_type(8)));
typedef float f32x4  __attribute__((ext_vector_type(4)));

__device__ __forceinline__ float sigm(float z) { return 1.f / (1.f + expf(-z)); }
__device__ __forceinline__ float bf2f(ushort u) {
    unsigned int b = ((unsigned int)u) << 16;
    return *(float*)&b;
}
__device__ __forceinline__ float agent_load(const float* p) {
    return __hip_atomic_load(p, __ATOMIC_RELAXED, __HIP_MEMORY_SCOPE_AGENT);
}

// ---------------- K0: merged prep (chlast | tables | ptsum | pack) -----------
__global__ __launch_bounds__(256) void k_prep(
    const float* __restrict__ lat_w, const float* __restrict__ imgt_w,
    const float* __restrict__ points,
    const float* __restrict__ f0, const float* __restrict__ f1,
    const float* __restrict__ f2, const float* __restrict__ f3,
    float* __restrict__ ws)
{
    __shared__ ushort s[32][280];      // chlast role
    __shared__ float s_pt[4][4];       // ptsum role
    int bid = blockIdx.x, t = threadIdx.x;

    if (bid < 638) {
        // ---- chlast: fpn fp32 NCHW -> bf16 channels-last, 32 px per block
        int bid2 = bid;
        int l, base, tpb;
        if (bid2 < 480)      { l = 0; base = 0;   tpb = 240; }
        else if (bid2 < 600) { l = 1; base = 480; tpb = 60; }
        else if (bid2 < 630) { l = 2; base = 600; tpb = 15; }
        else                 { l = 3; base = 630; tpb = 4; }
        const float* in = (l == 0) ? f0 : (l == 1) ? f1 : (l == 2) ? f2 : f3;
        const int npx_t[4] = {7680, 1920, 480, 120};
        const size_t ob_t[4] = {0, 3932160, 4915200, 5160960};
        int npx = npx_t[l];
        int local = bid2 - base;
        int b = local / tpb, ti = local % tpb;
        int px0 = ti * 32;
        int ci_g = t >> 3, pxq = t & 7;
        int px = px0 + pxq * 4;
        bool pv4 = px < npx;
        const float* ip = in + (size_t)b * 256 * npx + px;
#pragma unroll
        for (int c = 0; c < 8; ++c) {
            int ci = ci_g * 8 + c;
            float4 v = pv4 ? *(const float4*)(ip + (size_t)ci * npx)
                           : make_float4(0.f, 0.f, 0.f, 0.f);
            __hip_bfloat16 h0 = __float2bfloat16(v.x);
            __hip_bfloat16 h1 = __float2bfloat16(v.y);
            __hip_bfloat16 h2 = __float2bfloat16(v.z);
            __hip_bfloat16 h3 = __float2bfloat16(v.w);
            s[pxq * 4 + 0][ci] = *(ushort*)&h0;
            s[pxq * 4 + 1][ci] = *(ushort*)&h1;
            s[pxq * 4 + 2][ci] = *(ushort*)&h2;
            s[pxq * 4 + 3][ci] = *(ushort*)&h3;
        }
        __syncthreads();
        int pr = t >> 5, seg = t & 31;
        __hip_bfloat16* op = (__hip_bfloat16*)(ws + F_INBF) + ob_t[l] + (size_t)b * npx * 256;
#pragma unroll
        for (int k = 0; k < 4; ++k) {
            int pxl = pr + 8 * k;
            int pxw = px0 + pxl;
            if (pxw < npx) {
                uint4 v = *(const uint4*)&s[pxl][seg * 8];
                *(uint4*)&op[(size_t)pxw * 256 + seg * 8] = v;
            }
        }
    } else if (bid < 642) {
        // ---- tables + zero accumulators (POOLED 512 + GSUM 4096 + CNT 2)
        int gid = (bid - 638) * 256 + t;
        for (int i = gid; i < 4610; i += 1024) ws[F_POOLED + i] = 0.f;
        for (int idx = gid; idx < 4 * 48; idx += 1024) {
            int l = idx / 48, hh = idx % 48, h = 48 >> l;
            float r = 0.f;
            if (hh < h) {
                float step = (float)(h - 1) / 191.0f;
                for (int Y = 0; Y < 192; ++Y) {
                    float ys = step * (float)Y;
                    int y0 = (int)ys;
                    float f = ys - (float)y0;
                    int y1 = min(y0 + 1, h - 1);
                    if (y0 == hh) r += 1.f - f;
                    if (y1 == hh) r += f;
                }
            }
            ws[F_RY + idx] = r;
        }
        for (int idx = gid; idx < 4 * 160; idx += 1024) {
            int l = idx / 160, xx = idx % 160, w = 160 >> l;
            float r = 0.f;
            if (xx < w) {
                float step = (float)(w - 1) / 639.0f;
                for (int X = 0; X < 640; ++X) {
                    float xs = step * (float)X;
                    int x0 = (int)xs;
                    float f = xs - (float)x0;
                    int x1 = min(x0 + 1, w - 1);
                    if (x0 == xx) r += 1.f - f;
                    if (x1 == xx) r += f;
                }
            }
            ws[F_RX + idx] = r;
        }
    } else if (bid < 706) {
        // ---- ptsum partials
        int pb = bid - 642;
        int lane = t & 63, wid = t >> 6;
        float sx = 0.f, sy = 0.f, sz = 0.f, si = 0.f;
        int n0 = pb * 512;
#pragma unroll
        for (int k = 0; k < 2; ++k) {
            int n = n0 + k * 256 + t;
            const float* P = points + (size_t)n * 5;
            sx += P[1]; sy += P[2]; sz += P[3]; si += P[4];
        }
#pragma unroll
        for (int m = 32; m >= 1; m >>= 1) {
            sx += __shfl_xor(sx, m); sy += __shfl_xor(sy, m);
            sz += __shfl_xor(sz, m); si += __shfl_xor(si, m);
        }
        if (lane == 0) { s_pt[wid][0] = sx; s_pt[wid][1] = sy; s_pt[wid][2] = sz; s_pt[wid][3] = si; }
        __syncthreads();
        if (t < 4)
            ws[F_PTPART + pb * 4 + t] = s_pt[0][t] + s_pt[1][t] + s_pt[2][t] + s_pt[3][t];
    } else {
        // ---- pack lat_w + imgt_w -> bf16
        int idx = (bid - 706) * 256 + t;
        if (idx < 589824) {
            __hip_bfloat16* wp = (__hip_bfloat16*)(ws + F_WPACK);
            int e = idx & 7; int r = idx >> 3;
            int cm = r & 63; r >>= 6;
            int g = r & 3; r >>= 2;
            int tap = r % 9; r /= 9;
            int chunk = r & 7; int l = r >> 3;
            int ci = chunk * 32 + g * 8 + e;
            float v = lat_w[(((size_t)(l * 64 + cm)) * 256 + ci) * 9 + tap];
            wp[idx] = __float2bfloat16(v);
        } else {
            __hip_bfloat16* wb = (__hip_bfloat16*)(ws + F_IMGTBF);
            int i2 = idx - 589824;
            wb[i2] = __float2bfloat16(imgt_w[i2]);
        }
    }
}

// ---------------- K1: MFMA conv (+ last-block lw fold) -----------------------
__global__ __launch_bounds__(512) void k_conv_mfma(
    float* __restrict__ ws,
    const float* __restrict__ lat_b, const float* __restrict__ lat_s,
    const float* __restrict__ lat_o,
    const float* __restrict__ la_w1, const float* __restrict__ la_b1,
    const float* __restrict__ la_w2, const float* __restrict__ la_b2)
{
    __shared__ __hip_bfloat16 s_a[2][10][4][18][8];
    __shared__ __hip_bfloat16 s_b[2][9][4][64][8];
    __shared__ float s_red[4][64][32];
    __shared__ float s_hid[2][32];
    __shared__ bool amLast;
    const __hip_bfloat16* inbf = (const __hip_bfloat16*)(ws + F_INBF);
    const __hip_bfloat16* wp   = (const __hip_bfloat16*)(ws + F_WPACK);

    int bid = blockIdx.x;
    int l, base, tx_n, ty_n;
    if (bid < 120)      { l = 0; base = 0;   tx_n = 10; ty_n = 6; }
    else if (bid < 150) { l = 1; base = 120; tx_n = 5;  ty_n = 3; }
    else if (bid < 162) { l = 2; base = 150; tx_n = 3;  ty_n = 2; }
    else                { l = 3; base = 162; tx_n = 2;  ty_n = 1; }
    const int h_t[4] = {48, 24, 12, 6}, w_t[4] = {160, 80, 40, 20};
    const size_t ib_t[4] = {0, 3932160, 4915200, 5160960};
    const int co_t[4] = {CONV_OFF0, CONV_OFF1, CONV_OFF2, CONV_OFF3};
    int h = h_t[l], w = w_t[l];
    int local = bid - base, tpb = tx_n * ty_n;
    int b = local / tpb, r = local % tpb;
    int tyi = r / tx_n, txi = r % tx_n;
    int gy0 = tyi * 8, gx0 = txi * 16;

    int t = threadIdx.x;
    int half = t >> 8, lt = t & 255;
    int wl = lt >> 6, lane = t & 63;
    int xl = lane & 15, g = lane >> 4;

    const __hip_bfloat16* ibase = inbf + ib_t[l] + (size_t)b * h * w * 256;
    const __hip_bfloat16* wbase = wp + (size_t)l * 147456;

    f32x4 acc[2][4];
#pragma unroll
    for (int mi = 0; mi < 2; ++mi)
#pragma unroll
        for (int ni = 0; ni < 4; ++ni) acc[mi][ni] = (f32x4){0.f, 0.f, 0.f, 0.f};

    int ay = lt / 18, ax = lt % 18;
    for (int c = 0; c < 4; ++c) {
        int chunk = half * 4 + c;
        if (lt < 180) {
            int gy = gy0 - 1 + ay, gx = gx0 - 1 + ax;
            if (gy >= 0 && gy < h && gx >= 0 && gx < w) {
                const uint4* src = (const uint4*)(ibase + ((size_t)gy * w + gx) * 256 + chunk * 32);
#pragma unroll
                for (int gg = 0; gg < 4; ++gg) *(uint4*)&s_a[half][ay][gg][ax][0] = src[gg];
            } else {
                uint4 z = make_uint4(0, 0, 0, 0);
#pragma unroll
                for (int gg = 0; gg < 4; ++gg) *(uint4*)&s_a[half][ay][gg][ax][0] = z;
            }
        }
        {
            const uint4* src = (const uint4*)(wbase + (size_t)chunk * 18432);
            uint4* dst = (uint4*)&s_b[half][0][0][0][0];
#pragma unroll
            for (int k = 0; k < 9; ++k) dst[lt + k * 256] = src[lt + k * 256];
        }
        __syncthreads();
#pragma unroll
        for (int tap = 0; tap < 9; ++tap) {
            int ky = tap / 3, kx = tap % 3;
            bf16x8 af[2], bfr[4];
#pragma unroll
            for (int mi = 0; mi < 2; ++mi)
                af[mi] = *(const bf16x8*)&s_a[half][wl * 2 + mi + ky][g][xl + kx][0];
#pragma unroll
            for (int ni = 0; ni < 4; ++ni)
                bfr[ni] = *(const bf16x8*)&s_b[half][tap][g][ni * 16 + xl][0];
#pragma unroll
            for (int mi = 0; mi < 2; ++mi)
#pragma unroll
                for (int ni = 0; ni < 4; ++ni)
                    acc[mi][ni] = __builtin_amdgcn_mfma_f32_16x16x32_bf16(
                        af[mi], bfr[ni], acc[mi][ni], 0, 0, 0);
        }
        __syncthreads();
    }

    if (half == 1) {
#pragma unroll
        for (int mi = 0; mi < 2; ++mi)
#pragma unroll
            for (int ni = 0; ni < 4; ++ni)
                *(f32x4*)&s_red[wl][lane][mi * 16 + ni * 4] = acc[mi][ni];
    }
    __syncthreads();

    if (half == 0) {
#pragma unroll
        for (int mi = 0; mi < 2; ++mi)
#pragma unroll
            for (int ni = 0; ni < 4; ++ni) {
                f32x4 o = *(const f32x4*)&s_red[wl][lane][mi * 16 + ni * 4];
                acc[mi][ni] += o;
            }

        float bia[4], sca[4], off[4];
#pragma unroll
        for (int ni = 0; ni < 4; ++ni) {
            int cm = ni * 16 + xl;
            bia[ni] = lat_b[l * 64 + cm];
            sca[ni] = lat_s[l * 64 + cm];
            off[ni] = lat_o[l * 64 + cm];
        }
        float wsum[4] = {0.f, 0.f, 0.f, 0.f};
        __hip_bfloat16* conv = (__hip_bfloat16*)(ws + co_t[l]);
#pragma unroll
        for (int mi = 0; mi < 2; ++mi) {
            int oy = gy0 + wl * 2 + mi;
            bool yv = oy < h;
            float ry = yv ? ws[F_RY + l * 48 + oy] : 0.f;
#pragma unroll
            for (int j = 0; j < 4; ++j) {
                int ox = gx0 + g * 4 + j;
                bool v = yv && (ox < w);
                float rx = v ? ws[F_RX + l * 160 + ox] : 0.f;
                float rw = ry * rx;
                size_t rowb = (((size_t)b * h + oy) * w + ox) * 64;
#pragma unroll
                for (int ni = 0; ni < 4; ++ni) {
                    float val = fmaxf((acc[mi][ni][j] + bia[ni]) * sca[ni] + off[ni], 0.f);
                    if (v) {
                        conv[rowb + ni * 16 + xl] = __float2bfloat16(val);
                        wsum[ni] += val * rw;
                    }
                }
            }
        }
#pragma unroll
        for (int ni = 0; ni < 4; ++ni) {
            float s2 = wsum[ni];
            s2 += __shfl_xor(s2, 16);
            s2 += __shfl_xor(s2, 32);
            if (lane < 16) atomicAdd(ws + F_POOLED + b * 256 + l * 64 + ni * 16 + lane, s2);
        }
    }

    // ---- last-block lw fold: gates from POOLED (agent loads for coherence)
    __threadfence();
    if (t == 0)
        amLast = (atomicAdd((unsigned int*)(ws + F_CNT), 1u) == 165u);
    __syncthreads();
    if (!amLast) return;

    const float invHW = 1.f / (192.f * 640.f);
    if (t < 64) {
        int bb = t >> 5, j = t & 31;
        float acc2 = la_b1[j];
        const float* Wr = la_w1 + j * 256;
        for (int c = 0; c < 256; ++c)
            acc2 += agent_load(ws + F_POOLED + bb * 256 + c) * invHW * Wr[c];
        s_hid[bb][j] = fmaxf(acc2, 0.f);
    }
    __syncthreads();
    if (t < 8) {
        int bb = t >> 2, l2 = t & 3;
        float z = la_b2[l2];
        for (int j = 0; j < 32; ++j) z += s_hid[bb][j] * la_w2[l2 * 32 + j];
        ws[F_LWS + bb * 4 + l2] = 1.f + sigm(z);
    }
}

// ---------------- K3: gather (+ last-block se fold) --------------------------
// 16 thr/pt, 2048 blocks (8 waves/SIMD); 16-way striped gsum atomics.
__global__ __launch_bounds__(256) void k_gather3(
    float* __restrict__ ws, const float* __restrict__ points,
    const float* __restrict__ calib,
    const float* __restrict__ imgt_w, const float* __restrict__ imgt_b,
    const float* __restrict__ imgt_s, const float* __restrict__ imgt_o,
    const float* __restrict__ pts_w, const float* __restrict__ pts_b,
    const float* __restrict__ pts_s, const float* __restrict__ pts_o,
    const float* __restrict__ w1p, const float* __restrict__ w2p,
    const float* __restrict__ w1i, const float* __restrict__ w2i,
    float* __restrict__ dout)
{
    __shared__ float s_part[4][256];   // [wave][column]
    __shared__ float s_se[772];        // gsum 256 | cross 256 | h 256 | pt4 4
    __shared__ bool amLast;
    int t = threadIdx.x;
    int p = t >> 4, sub = t & 15;
    int l = sub >> 2, q16 = (sub & 3) * 16;
    int wid = t >> 6, lane = t & 63;
    int n = blockIdx.x * 16 + p;
    int b = n >> 14;

    const float* P = points + (size_t)n * 5;
    float px = P[1], py = P[2], pz = P[3];
    const float* C = calib + b * 12;
    float pu = C[0] * px + C[1] * py + C[2]  * pz + C[3];
    float pv = C[4] * px + C[5] * py + C[6]  * pz + C[7];
    float pw = C[8] * px + C[9] * py + C[10] * pz + C[11];
    float zs = fmaxf(pw, 1e-5f);
    float u = pu / zs, v = pv / zs;
    bool on = (u >= 0.f) && (u < 640.f) && (v >= 0.f) && (v < 192.f) && (pw > 1e-5f);
    int ui = min(max((int)u, 0), 639);
    int vi = min(max((int)v, 0), 191);

    int h = 48 >> l, w = 160 >> l;
    float ys = (float)vi * (float)(h - 1) * (1.f / 191.f);
    int y0 = (int)ys; float fy = ys - (float)y0; int y1 = min(y0 + 1, h - 1);
    float xs = (float)ui * (float)(w - 1) * (1.f / 639.f);
    int x0 = (int)xs; float fx = xs - (float)x0; int x1 = min(x0 + 1, w - 1);
    const int co_t[4] = {CONV_OFF0, CONV_OFF1, CONV_OFF2, CONV_OFF3};
    const ushort* base = (const ushort*)(ws + co_t[l]) + (size_t)b * h * w * 64 + q16;
    const ushort* A00 = base + ((size_t)y0 * w + x0) * 64;
    const ushort* A01 = base + ((size_t)y0 * w + x1) * 64;
    const ushort* A10 = base + ((size_t)y1 * w + x0) * 64;
    const ushort* A11 = base + ((size_t)y1 * w + x1) * 64;
    float sc = on ? ws[F_LWS + b * 4 + l] : 0.f;
    float W00 = (1.f - fy) * (1.f - fx) * sc, W01 = (1.f - fy) * fx * sc;
    float W10 = fy * (1.f - fx) * sc,         W11 = fy * fx * sc;

    uint4 va[2], vb[2], vc[2], vd[2];
#pragma unroll
    for (int q = 0; q < 2; ++q) {
        va[q] = *(const uint4*)(A00 + q * 8);
        vb[q] = *(const uint4*)(A01 + q * 8);
        vc[q] = *(const uint4*)(A10 + q * 8);
        vd[q] = *(const uint4*)(A11 + q * 8);
    }

    float r[16];
#pragma unroll
    for (int q = 0; q < 2; ++q) {
        const ushort* ea = (const ushort*)&va[q];
        const ushort* eb = (const ushort*)&vb[q];
        const ushort* ec = (const ushort*)&vc[q];
        const ushort* ed = (const ushort*)&vd[q];
#pragma unroll
        for (int i = 0; i < 8; ++i)
            r[q * 8 + i] = W00 * bf2f(ea[i]) + W01 * bf2f(eb[i])
                         + W10 * bf2f(ec[i]) + W11 * bf2f(ed[i]);
    }

    ushort* orow = (ushort*)dout + (size_t)n * 256 + l * 64 + q16;
#pragma unroll
    for (int q = 0; q < 2; ++q) {
        ushort pk[8];
#pragma unroll
        for (int i = 0; i < 8; ++i) {
            __hip_bfloat16 hb = __float2bfloat16(r[q * 8 + i]);
            pk[i] = *(ushort*)&hb;
        }
        *(uint4*)(orow + q * 8) = *(uint4*)pk;
    }

    // column sums over the 4 points of this wave (lane bits 4,5)
#pragma unroll
    for (int i = 0; i < 16; ++i) {
        float s = r[i];
        s += __shfl_xor(s, 16);
        s += __shfl_xor(s, 32);
        r[i] = s;
    }
    if (lane < 16) {
#pragma unroll
        for (int i = 0; i < 16; ++i)
            s_part[wid][(lane >> 2) * 64 + (lane & 3) * 16 + i] = r[i];
    }
    __syncthreads();
    {
        float s = s_part[0][t] + s_part[1][t] + s_part[2][t] + s_part[3][t];
        atomicAdd(ws + F_GSUM + (blockIdx.x & 15) * 256 + t, s);
    }

    // ---- last-block se fold
    __threadfence();
    if (t == 0)
        amLast = (atomicAdd((unsigned int*)(ws + F_CNT + 1), 1u) == 2047u);
    __syncthreads();
    if (!amLast) return;

    float* s_gsum  = s_se;
    float* s_cross = s_se + 256;
    float* s_h     = s_se + 512;
    float* s_pt4   = s_se + 768;
    const float invN = 1.f / (float)NPTS;
    {
        float s = 0.f;
#pragma unroll
        for (int rep = 0; rep < 16; ++rep)
            s += agent_load(ws + F_GSUM + rep * 256 + t);
        s_gsum[t] = s;
    }
    if (t < 4) {
        float acc = 0.f;
        for (int bb = 0; bb < 64; ++bb) acc += ws[F_PTPART + bb * 4 + t];
        s_pt4[t] = acc;
    }
    __syncthreads();
    if (t < 128) {
        float a = 0.f;
        const float* Wr = imgt_w + (size_t)t * 256;
        for (int c = 0; c < 256; c += 4) {
            float4 gc = *(const float4*)(s_gsum + c);
            float4 wc = *(const float4*)(Wr + c);
            a += gc.x * wc.x + gc.y * wc.y + gc.z * wc.z + gc.w * wc.w;
        }
        s_cross[t] = (a * invN + imgt_b[t]) * imgt_s[t] + imgt_o[t];
    } else {
        int o = t - 128;
        float pp = 0.f;
        for (int k = 0; k < 4; ++k) pp += s_pt4[k] * invN * pts_w[o * 4 + k];
        s_cross[128 + o] = (pp + pts_b[o]) * pts_s[o] + pts_o[o];
    }
    __syncthreads();
    {
        int br = t >> 7, o = t & 127;
        const float* W = br ? w1i : w1p;
        const float* Wr = W + (size_t)o * 256;
        float hh = 0.f;
        for (int c = 0; c < 256; c += 4) {
            float4 cc = *(const float4*)(s_cross + c);
            float4 wc = *(const float4*)(Wr + c);
            hh += cc.x * wc.x + cc.y * wc.y + cc.z * wc.z + cc.w * wc.w;
        }
        s_h[t] = fmaxf(hh, 0.f);
    }
    __syncthreads();
    {
        int br = t >> 7, o = t & 127;
        const float* W2 = br ? w2i : w2p;
        const float* Wr = W2 + (size_t)o * 128;
        const float* hb = s_h + br * 128;
        float gg = 0.f;
        for (int c = 0; c < 128; c += 4) {
            float4 hc = *(const float4*)(hb + c);
            float4 wc = *(const float4*)(Wr + c);
            gg += hc.x * wc.x + hc.y * wc.y + hc.z * wc.z + hc.w * wc.w;
        }
        ws[F_GATES + br * 128 + o] = 1.f + sigm(gg);
    }
}

// ---------------- K5: MFMA img transform + fully fused epilogue --------------
__global__ __launch_bounds__(256) void k_gemmfuse(
    float* __restrict__ ws, const float* __restrict__ points,
    const float* __restrict__ imgt_b, const float* __restrict__ imgt_s,
    const float* __restrict__ imgt_o,
    const float* __restrict__ pts_w, const float* __restrict__ pts_b,
    const float* __restrict__ pts_s, const float* __restrict__ pts_o,
    float* __restrict__ dout)
{
    __shared__ __hip_bfloat16 s_a[8][4][64][8];
    const ushort* wbf = (const ushort*)(ws + F_IMGTBF);
    int t = threadIdx.x;
    int wid = t >> 6, lane = t & 63, xl = lane & 15, g = lane >> 4;
    int n0 = blockIdx.x * 64;

    {
        int nl = t >> 2, kq = t & 3;
        const uint4* src = (const uint4*)((const ushort*)dout + (size_t)(n0 + nl) * 256) + kq * 8;
#pragma unroll
        for (int kk = 0; kk < 8; ++kk) {
            uint4 v = src[kk];
            int k = kq * 8 + kk;
            *(uint4*)&s_a[k >> 2][k & 3][nl][0] = v;
        }
    }
    __syncthreads();

    f32x4 acc[8];
#pragma unroll
    for (int ni = 0; ni < 8; ++ni) acc[ni] = (f32x4){0.f, 0.f, 0.f, 0.f};

    for (int chunk = 0; chunk < 8; ++chunk) {
        bf16x8 af = *(const bf16x8*)&s_a[chunk][g][wid * 16 + xl][0];
#pragma unroll
        for (int ni = 0; ni < 8; ++ni) {
            bf16x8 bfr = *(const bf16x8*)(wbf + (size_t)(ni * 16 + xl) * 256 + chunk * 32 + g * 8);
            acc[ni] = __builtin_amdgcn_mfma_f32_16x16x32_bf16(af, bfr, acc[ni], 0, 0, 0);
        }
    }

    float4 Pt[4];
#pragma unroll
    for (int j = 0; j < 4; ++j) {
        int np = n0 + wid * 16 + g * 4 + j;
        Pt[j] = *(const float4*)(points + (size_t)np * 5 + 1);
    }
#pragma unroll
    for (int ni = 0; ni < 8; ++ni) {
        int o = ni * 16 + xl;
        float ib = imgt_b[o], isc = imgt_s[o], io = imgt_o[o];
        float gp = ws[F_GATES + o], gi = ws[F_GATES + 128 + o];
        float4 pwv = *(const float4*)(pts_w + o * 4);
        float pb = pts_b[o], psc = pts_s[o], po = pts_o[o];
#pragma unroll
        for (int j = 0; j < 4; ++j) {
            int np = n0 + wid * 16 + g * 4 + j;
            float img = (acc[ni][j] + ib) * isc + io;
            float4 pt = Pt[j];
            float pp = (pt.x * pwv.x + pt.y * pwv.y + pt.z * pwv.z + pt.w * pwv.w + pb) * psc + po;
            dout[(size_t)np * 128 + o] = fmaxf(img * gp + pp * gi, 0.f);
        }
    }
}

// ---------------- launch ------------------------------------------------------
extern "C" void kernel_launch(void* const* d_in, const int* in_sizes, int n_in,
                              void* d_out, int out_size, void* d_ws, size_t ws_size,
                              hipStream_t stream)
{
    const float* fpn0 = (const float*)d_in[0];
    const float* fpn1 = (const float*)d_in[1];
    const float* fpn2 = (const float*)d_in[2];
    const float* fpn3 = (const float*)d_in[3];
    const float* points = (const float*)d_in[4];
    const float* calib  = (const float*)d_in[5];
    const float* lat_w  = (const float*)d_in[6];
    const float* lat_b  = (const float*)d_in[7];
    const float* lat_s  = (const float*)d_in[8];
    const float* lat_o  = (const float*)d_in[9];
    const float* pts_w  = (const float*)d_in[10];
    const float* pts_b  = (const float*)d_in[11];
    const float* pts_s  = (const float*)d_in[12];
    const float* pts_o  = (const float*)d_in[13];
    const float* imgt_w = (const float*)d_in[14];
    const float* imgt_b = (const float*)d_in[15];
    const float* imgt_s = (const float*)d_in[16];
    const float* imgt_o = (const float*)d_in[17];
    const float* la_w1  = (const float*)d_in[18];
    const float* la_b1  = (const float*)d_in[19];
    const float* la_w2  = (const float*)d_in[20];
    const float* la_b2  = (const float*)d_in[21];
    const float* se_pt_w1  = (const float*)d_in[22];
    const float* se_pt_w2  = (const float*)d_in[23];
    const float* se_img_w1 = (const float*)d_in[24];
    const float* se_img_w2 = (const float*)d_in[25];

    float* ws = (float*)d_ws;
    float* dout = (float*)d_out;

    k_prep<<<3138, 256, 0, stream>>>(lat_w, imgt_w, points,
                                     fpn0, fpn1, fpn2, fpn3, ws);
    k_conv_mfma<<<166, 512, 0, stream>>>(ws, lat_b, lat_s, lat_o,
                                         la_w1, la_b1, la_w2, la_b2);
    k_gather3<<<2048, 256, 0, stream>>>(ws, points, calib,
                                        imgt_w, imgt_b, imgt_s, imgt_o,
                                        pts_w, pts_b, pts_s, pts_o,
                                        se_pt_w1, se_pt_w2, se_img_w1, se_img_w2,
                                        dout);
    k_gemmfuse<<<512, 256, 0, stream>>>(ws, points, imgt_b, imgt_s, imgt_o,
                                        pts_w, pts_b, pts_s, pts_o, dout);
}

// Round 18
// 117.038 us; speedup vs baseline: 3.1830x; 3.1830x over previous
//
#include <hip/hip_runtime.h>
#include <hip/hip_bf16.h>
#include <math.h>

#define NPTS   32768

// Workspace float offsets
#define CONV_OFF0 0         // conv outputs bf16 channels-last
#define CONV_OFF1 983040
#define CONV_OFF2 1228800
#define CONV_OFF3 1290240
#define F_RY     1312256   // float[4][48]
#define F_RX     1312448   // float[4][160]
#define F_POOLED 1313088   // float[2][256]  (zeroed; conv atomics)
#define F_GSUM   1313600   // float[16][256] (zeroed; 16-way striped gather atomics)
#define F_LWS    1317696   // float[2][4]    (written by k_lw)
#define F_GATES  1317704   // float[2][128]  (written by k_se)
#define F_PTPART 1317960   // float[64][4]   (fully written by prep blocks)
#define F_INBF   1318272   // bf16 channels-last inputs: 5,222,400 bf16 ele
#define INBF_ELE 5222400
#define F_WPACK  (F_INBF + INBF_ELE/2)    // bf16 packed lat weights
#define F_IMGTBF (F_WPACK + 294912)       // bf16 imgt_w -> ends ~16.96 MB

typedef short bf16x8 __attribute__((ext_vector_type(8)));
typedef float f32x4  __attribute__((ext_vector_type(4)));

__device__ __forceinline__ float sigm(float z) { return 1.f / (1.f + expf(-z)); }
__device__ __forceinline__ float bf2f(ushort u) {
    unsigned int b = ((unsigned int)u) << 16;
    return *(float*)&b;
}

// ---------------- K0: merged prep (chlast | tables | ptsum | pack) -----------
__global__ __launch_bounds__(256) void k_prep(
    const float* __restrict__ lat_w, const float* __restrict__ imgt_w,
    const float* __restrict__ points,
    const float* __restrict__ f0, const float* __restrict__ f1,
    const float* __restrict__ f2, const float* __restrict__ f3,
    float* __restrict__ ws)
{
    __shared__ ushort s[32][280];      // chlast role
    __shared__ float s_pt[4][4];       // ptsum role
    int bid = blockIdx.x, t = threadIdx.x;

    if (bid < 638) {
        // ---- chlast: fpn fp32 NCHW -> bf16 channels-last, 32 px per block
        int bid2 = bid;
        int l, base, tpb;
        if (bid2 < 480)      { l = 0; base = 0;   tpb = 240; }
        else if (bid2 < 600) { l = 1; base = 480; tpb = 60; }
        else if (bid2 < 630) { l = 2; base = 600; tpb = 15; }
        else                 { l = 3; base = 630; tpb = 4; }
        const float* in = (l == 0) ? f0 : (l == 1) ? f1 : (l == 2) ? f2 : f3;
        const int npx_t[4] = {7680, 1920, 480, 120};
        const size_t ob_t[4] = {0, 3932160, 4915200, 5160960};
        int npx = npx_t[l];
        int local = bid2 - base;
        int b = local / tpb, ti = local % tpb;
        int px0 = ti * 32;
        int ci_g = t >> 3, pxq = t & 7;
        int px = px0 + pxq * 4;
        bool pv4 = px < npx;
        const float* ip = in + (size_t)b * 256 * npx + px;
#pragma unroll
        for (int c = 0; c < 8; ++c) {
            int ci = ci_g * 8 + c;
            float4 v = pv4 ? *(const float4*)(ip + (size_t)ci * npx)
                           : make_float4(0.f, 0.f, 0.f, 0.f);
            __hip_bfloat16 h0 = __float2bfloat16(v.x);
            __hip_bfloat16 h1 = __float2bfloat16(v.y);
            __hip_bfloat16 h2 = __float2bfloat16(v.z);
            __hip_bfloat16 h3 = __float2bfloat16(v.w);
            s[pxq * 4 + 0][ci] = *(ushort*)&h0;
            s[pxq * 4 + 1][ci] = *(ushort*)&h1;
            s[pxq * 4 + 2][ci] = *(ushort*)&h2;
            s[pxq * 4 + 3][ci] = *(ushort*)&h3;
        }
        __syncthreads();
        int pr = t >> 5, seg = t & 31;
        __hip_bfloat16* op = (__hip_bfloat16*)(ws + F_INBF) + ob_t[l] + (size_t)b * npx * 256;
#pragma unroll
        for (int k = 0; k < 4; ++k) {
            int pxl = pr + 8 * k;
            int pxw = px0 + pxl;
            if (pxw < npx) {
                uint4 v = *(const uint4*)&s[pxl][seg * 8];
                *(uint4*)&op[(size_t)pxw * 256 + seg * 8] = v;
            }
        }
    } else if (bid < 642) {
        // ---- tables + zero accumulators (POOLED 512 + GSUM 16x256)
        int gid = (bid - 638) * 256 + t;
        for (int i = gid; i < 4608; i += 1024) ws[F_POOLED + i] = 0.f;
        for (int idx = gid; idx < 4 * 48; idx += 1024) {
            int l = idx / 48, hh = idx % 48, h = 48 >> l;
            float r = 0.f;
            if (hh < h) {
                float step = (float)(h - 1) / 191.0f;
                for (int Y = 0; Y < 192; ++Y) {
                    float ys = step * (float)Y;
                    int y0 = (int)ys;
                    float f = ys - (float)y0;
                    int y1 = min(y0 + 1, h - 1);
                    if (y0 == hh) r += 1.f - f;
                    if (y1 == hh) r += f;
                }
            }
            ws[F_RY + idx] = r;
        }
        for (int idx = gid; idx < 4 * 160; idx += 1024) {
            int l = idx / 160, xx = idx % 160, w = 160 >> l;
            float r = 0.f;
            if (xx < w) {
                float step = (float)(w - 1) / 639.0f;
                for (int X = 0; X < 640; ++X) {
                    float xs = step * (float)X;
                    int x0 = (int)xs;
                    float f = xs - (float)x0;
                    int x1 = min(x0 + 1, w - 1);
                    if (x0 == xx) r += 1.f - f;
                    if (x1 == xx) r += f;
                }
            }
            ws[F_RX + idx] = r;
        }
    } else if (bid < 706) {
        // ---- ptsum partials
        int pb = bid - 642;
        int lane = t & 63, wid = t >> 6;
        float sx = 0.f, sy = 0.f, sz = 0.f, si = 0.f;
        int n0 = pb * 512;
#pragma unroll
        for (int k = 0; k < 2; ++k) {
            int n = n0 + k * 256 + t;
            const float* P = points + (size_t)n * 5;
            sx += P[1]; sy += P[2]; sz += P[3]; si += P[4];
        }
#pragma unroll
        for (int m = 32; m >= 1; m >>= 1) {
            sx += __shfl_xor(sx, m); sy += __shfl_xor(sy, m);
            sz += __shfl_xor(sz, m); si += __shfl_xor(si, m);
        }
        if (lane == 0) { s_pt[wid][0] = sx; s_pt[wid][1] = sy; s_pt[wid][2] = sz; s_pt[wid][3] = si; }
        __syncthreads();
        if (t < 4)
            ws[F_PTPART + pb * 4 + t] = s_pt[0][t] + s_pt[1][t] + s_pt[2][t] + s_pt[3][t];
    } else {
        // ---- pack lat_w + imgt_w -> bf16
        int idx = (bid - 706) * 256 + t;
        if (idx < 589824) {
            __hip_bfloat16* wp = (__hip_bfloat16*)(ws + F_WPACK);
            int e = idx & 7; int r = idx >> 3;
            int cm = r & 63; r >>= 6;
            int g = r & 3; r >>= 2;
            int tap = r % 9; r /= 9;
            int chunk = r & 7; int l = r >> 3;
            int ci = chunk * 32 + g * 8 + e;
            float v = lat_w[(((size_t)(l * 64 + cm)) * 256 + ci) * 9 + tap];
            wp[idx] = __float2bfloat16(v);
        } else {
            __hip_bfloat16* wb = (__hip_bfloat16*)(ws + F_IMGTBF);
            int i2 = idx - 589824;
            wb[i2] = __float2bfloat16(imgt_w[i2]);
        }
    }
}

// ---------------- K1: MFMA conv, 8 waves, K-split; bf16 channels-last out ----
__global__ __launch_bounds__(512) void k_conv_mfma(
    float* __restrict__ ws,
    const float* __restrict__ lat_b, const float* __restrict__ lat_s,
    const float* __restrict__ lat_o)
{
    __shared__ __hip_bfloat16 s_a[2][10][4][18][8];
    __shared__ __hip_bfloat16 s_b[2][9][4][64][8];
    __shared__ float s_red[4][64][32];
    const __hip_bfloat16* inbf = (const __hip_bfloat16*)(ws + F_INBF);
    const __hip_bfloat16* wp   = (const __hip_bfloat16*)(ws + F_WPACK);

    int bid = blockIdx.x;
    int l, base, tx_n, ty_n;
    if (bid < 120)      { l = 0; base = 0;   tx_n = 10; ty_n = 6; }
    else if (bid < 150) { l = 1; base = 120; tx_n = 5;  ty_n = 3; }
    else if (bid < 162) { l = 2; base = 150; tx_n = 3;  ty_n = 2; }
    else                { l = 3; base = 162; tx_n = 2;  ty_n = 1; }
    const int h_t[4] = {48, 24, 12, 6}, w_t[4] = {160, 80, 40, 20};
    const size_t ib_t[4] = {0, 3932160, 4915200, 5160960};
    const int co_t[4] = {CONV_OFF0, CONV_OFF1, CONV_OFF2, CONV_OFF3};
    int h = h_t[l], w = w_t[l];
    int local = bid - base, tpb = tx_n * ty_n;
    int b = local / tpb, r = local % tpb;
    int tyi = r / tx_n, txi = r % tx_n;
    int gy0 = tyi * 8, gx0 = txi * 16;

    int t = threadIdx.x;
    int half = t >> 8, lt = t & 255;
    int wl = lt >> 6, lane = t & 63;
    int xl = lane & 15, g = lane >> 4;

    const __hip_bfloat16* ibase = inbf + ib_t[l] + (size_t)b * h * w * 256;
    const __hip_bfloat16* wbase = wp + (size_t)l * 147456;

    f32x4 acc[2][4];
#pragma unroll
    for (int mi = 0; mi < 2; ++mi)
#pragma unroll
        for (int ni = 0; ni < 4; ++ni) acc[mi][ni] = (f32x4){0.f, 0.f, 0.f, 0.f};

    int ay = lt / 18, ax = lt % 18;
    for (int c = 0; c < 4; ++c) {
        int chunk = half * 4 + c;
        if (lt < 180) {
            int gy = gy0 - 1 + ay, gx = gx0 - 1 + ax;
            if (gy >= 0 && gy < h && gx >= 0 && gx < w) {
                const uint4* src = (const uint4*)(ibase + ((size_t)gy * w + gx) * 256 + chunk * 32);
#pragma unroll
                for (int gg = 0; gg < 4; ++gg) *(uint4*)&s_a[half][ay][gg][ax][0] = src[gg];
            } else {
                uint4 z = make_uint4(0, 0, 0, 0);
#pragma unroll
                for (int gg = 0; gg < 4; ++gg) *(uint4*)&s_a[half][ay][gg][ax][0] = z;
            }
        }
        {
            const uint4* src = (const uint4*)(wbase + (size_t)chunk * 18432);
            uint4* dst = (uint4*)&s_b[half][0][0][0][0];
#pragma unroll
            for (int k = 0; k < 9; ++k) dst[lt + k * 256] = src[lt + k * 256];
        }
        __syncthreads();
#pragma unroll
        for (int tap = 0; tap < 9; ++tap) {
            int ky = tap / 3, kx = tap % 3;
            bf16x8 af[2], bfr[4];
#pragma unroll
            for (int mi = 0; mi < 2; ++mi)
                af[mi] = *(const bf16x8*)&s_a[half][wl * 2 + mi + ky][g][xl + kx][0];
#pragma unroll
            for (int ni = 0; ni < 4; ++ni)
                bfr[ni] = *(const bf16x8*)&s_b[half][tap][g][ni * 16 + xl][0];
#pragma unroll
            for (int mi = 0; mi < 2; ++mi)
#pragma unroll
                for (int ni = 0; ni < 4; ++ni)
                    acc[mi][ni] = __builtin_amdgcn_mfma_f32_16x16x32_bf16(
                        af[mi], bfr[ni], acc[mi][ni], 0, 0, 0);
        }
        __syncthreads();
    }

    if (half == 1) {
#pragma unroll
        for (int mi = 0; mi < 2; ++mi)
#pragma unroll
            for (int ni = 0; ni < 4; ++ni)
                *(f32x4*)&s_red[wl][lane][mi * 16 + ni * 4] = acc[mi][ni];
    }
    __syncthreads();
    if (half == 1) return;

#pragma unroll
    for (int mi = 0; mi < 2; ++mi)
#pragma unroll
        for (int ni = 0; ni < 4; ++ni) {
            f32x4 o = *(const f32x4*)&s_red[wl][lane][mi * 16 + ni * 4];
            acc[mi][ni] += o;
        }

    float bia[4], sca[4], off[4];
#pragma unroll
    for (int ni = 0; ni < 4; ++ni) {
        int cm = ni * 16 + xl;
        bia[ni] = lat_b[l * 64 + cm];
        sca[ni] = lat_s[l * 64 + cm];
        off[ni] = lat_o[l * 64 + cm];
    }
    float wsum[4] = {0.f, 0.f, 0.f, 0.f};
    __hip_bfloat16* conv = (__hip_bfloat16*)(ws + co_t[l]);
#pragma unroll
    for (int mi = 0; mi < 2; ++mi) {
        int oy = gy0 + wl * 2 + mi;
        bool yv = oy < h;
        float ry = yv ? ws[F_RY + l * 48 + oy] : 0.f;
#pragma unroll
        for (int j = 0; j < 4; ++j) {
            int ox = gx0 + g * 4 + j;
            bool v = yv && (ox < w);
            float rx = v ? ws[F_RX + l * 160 + ox] : 0.f;
            float rw = ry * rx;
            size_t rowb = (((size_t)b * h + oy) * w + ox) * 64;
#pragma unroll
            for (int ni = 0; ni < 4; ++ni) {
                float val = fmaxf((acc[mi][ni][j] + bia[ni]) * sca[ni] + off[ni], 0.f);
                if (v) {
                    conv[rowb + ni * 16 + xl] = __float2bfloat16(val);
                    wsum[ni] += val * rw;
                }
            }
        }
    }
#pragma unroll
    for (int ni = 0; ni < 4; ++ni) {
        float s2 = wsum[ni];
        s2 += __shfl_xor(s2, 16);
        s2 += __shfl_xor(s2, 32);
        if (lane < 16) atomicAdd(ws + F_POOLED + b * 256 + l * 64 + ni * 16 + lane, s2);
    }
}

// ---------------- K2b: level-attention gates lw (1 block — cheap) ------------
__global__ void k_lw(float* __restrict__ ws,
                     const float* __restrict__ la_w1, const float* __restrict__ la_b1,
                     const float* __restrict__ la_w2, const float* __restrict__ la_b2)
{
    __shared__ float s_hid[2][32];
    int t = threadIdx.x;
    const float invHW = 1.f / (192.f * 640.f);
    if (t < 64) {
        int bb = t >> 5, j = t & 31;
        float acc = la_b1[j];
        const float* P = ws + F_POOLED + bb * 256;
        const float* Wr = la_w1 + j * 256;
        for (int c = 0; c < 256; c += 4) {
            float4 pc = *(const float4*)(P + c);
            float4 wc = *(const float4*)(Wr + c);
            acc += (pc.x * wc.x + pc.y * wc.y + pc.z * wc.z + pc.w * wc.w) * invHW;
        }
        s_hid[bb][j] = fmaxf(acc, 0.f);
    }
    __syncthreads();
    if (t < 8) {
        int bb = t >> 2, l = t & 3;
        float z = la_b2[l];
        for (int j = 0; j < 32; ++j) z += s_hid[bb][j] * la_w2[l * 32 + j];
        ws[F_LWS + bb * 4 + l] = 1.f + sigm(z);
    }
}

// ---------------- K3: project+gather -> bf16 gath; 16 thr/pt, 2048 blocks ----
__global__ __launch_bounds__(256) void k_gather3(
    float* __restrict__ ws, const float* __restrict__ points,
    const float* __restrict__ calib, float* __restrict__ dout)
{
    __shared__ float s_part[4][256];   // [wave][column]
    int t = threadIdx.x;
    int p = t >> 4, sub = t & 15;
    int l = sub >> 2, q16 = (sub & 3) * 16;
    int wid = t >> 6, lane = t & 63;
    int n = blockIdx.x * 16 + p;
    int b = n >> 14;

    const float* P = points + (size_t)n * 5;
    float px = P[1], py = P[2], pz = P[3];
    const float* C = calib + b * 12;
    float pu = C[0] * px + C[1] * py + C[2]  * pz + C[3];
    float pv = C[4] * px + C[5] * py + C[6]  * pz + C[7];
    float pw = C[8] * px + C[9] * py + C[10] * pz + C[11];
    float zs = fmaxf(pw, 1e-5f);
    float u = pu / zs, v = pv / zs;
    bool on = (u >= 0.f) && (u < 640.f) && (v >= 0.f) && (v < 192.f) && (pw > 1e-5f);
    int ui = min(max((int)u, 0), 639);
    int vi = min(max((int)v, 0), 191);

    int h = 48 >> l, w = 160 >> l;
    float ys = (float)vi * (float)(h - 1) * (1.f / 191.f);
    int y0 = (int)ys; float fy = ys - (float)y0; int y1 = min(y0 + 1, h - 1);
    float xs = (float)ui * (float)(w - 1) * (1.f / 639.f);
    int x0 = (int)xs; float fx = xs - (float)x0; int x1 = min(x0 + 1, w - 1);
    const int co_t[4] = {CONV_OFF0, CONV_OFF1, CONV_OFF2, CONV_OFF3};
    const ushort* base = (const ushort*)(ws + co_t[l]) + (size_t)b * h * w * 64 + q16;
    const ushort* A00 = base + ((size_t)y0 * w + x0) * 64;
    const ushort* A01 = base + ((size_t)y0 * w + x1) * 64;
    const ushort* A10 = base + ((size_t)y1 * w + x0) * 64;
    const ushort* A11 = base + ((size_t)y1 * w + x1) * 64;
    float sc = on ? ws[F_LWS + b * 4 + l] : 0.f;
    float W00 = (1.f - fy) * (1.f - fx) * sc, W01 = (1.f - fy) * fx * sc;
    float W10 = fy * (1.f - fx) * sc,         W11 = fy * fx * sc;

    // 8 independent 16B corner loads (2 per corner)
    uint4 va[2], vb[2], vc[2], vd[2];
#pragma unroll
    for (int q = 0; q < 2; ++q) {
        va[q] = *(const uint4*)(A00 + q * 8);
        vb[q] = *(const uint4*)(A01 + q * 8);
        vc[q] = *(const uint4*)(A10 + q * 8);
        vd[q] = *(const uint4*)(A11 + q * 8);
    }

    float r[16];
#pragma unroll
    for (int q = 0; q < 2; ++q) {
        const ushort* ea = (const ushort*)&va[q];
        const ushort* eb = (const ushort*)&vb[q];
        const ushort* ec = (const ushort*)&vc[q];
        const ushort* ed = (const ushort*)&vd[q];
#pragma unroll
        for (int i = 0; i < 8; ++i)
            r[q * 8 + i] = W00 * bf2f(ea[i]) + W01 * bf2f(eb[i])
                         + W10 * bf2f(ec[i]) + W11 * bf2f(ed[i]);
    }

    // pack + store 32 B contiguous; 16 threads cover a full 512 B row
    ushort* orow = (ushort*)dout + (size_t)n * 256 + l * 64 + q16;
#pragma unroll
    for (int q = 0; q < 2; ++q) {
        ushort pk[8];
#pragma unroll
        for (int i = 0; i < 8; ++i) {
            __hip_bfloat16 hb = __float2bfloat16(r[q * 8 + i]);
            pk[i] = *(ushort*)&hb;
        }
        *(uint4*)(orow + q * 8) = *(uint4*)pk;
    }

    // column sums over the 4 points of this wave (lane bits 4,5)
#pragma unroll
    for (int i = 0; i < 16; ++i) {
        float s = r[i];
        s += __shfl_xor(s, 16);
        s += __shfl_xor(s, 32);
        r[i] = s;
    }
    if (lane < 16) {   // lane == sub: holds full per-sub partial (16 channels)
#pragma unroll
        for (int i = 0; i < 16; ++i)
            s_part[wid][(lane >> 2) * 64 + (lane & 3) * 16 + i] = r[i];
    }
    __syncthreads();
    {
        float s = s_part[0][t] + s_part[1][t] + s_part[2][t] + s_part[3][t];
        atomicAdd(ws + F_GSUM + (blockIdx.x & 15) * 256 + t, s);
    }
}

// ---------------- K4: SE gates (256 threads; merge 16 gsum replicas) ---------
__global__ __launch_bounds__(256) void k_se(float* __restrict__ ws,
                     const float* __restrict__ imgt_w, const float* __restrict__ imgt_b,
                     const float* __restrict__ imgt_s, const float* __restrict__ imgt_o,
                     const float* __restrict__ pts_w, const float* __restrict__ pts_b,
                     const float* __restrict__ pts_s, const float* __restrict__ pts_o,
                     const float* __restrict__ w1p, const float* __restrict__ w2p,
                     const float* __restrict__ w1i, const float* __restrict__ w2i)
{
    __shared__ float s_gsum[256];
    __shared__ float s_cross[256];
    __shared__ float s_h[256];
    __shared__ float s_pt4[4];
    int t = threadIdx.x;  // 256
    const float invN = 1.f / (float)NPTS;
    {
        float s = 0.f;
#pragma unroll
        for (int rep = 0; rep < 16; ++rep) s += ws[F_GSUM + rep * 256 + t];
        s_gsum[t] = s;
    }
    if (t < 4) {
        float acc = 0.f;
        for (int bb = 0; bb < 64; ++bb) acc += ws[F_PTPART + bb * 4 + t];
        s_pt4[t] = acc;
    }
    __syncthreads();
    if (t < 128) {
        float a = 0.f;
        const float* Wr = imgt_w + (size_t)t * 256;
        for (int c = 0; c < 256; c += 4) {
            float4 gc = *(const float4*)(s_gsum + c);
            float4 wc = *(const float4*)(Wr + c);
            a += gc.x * wc.x + gc.y * wc.y + gc.z * wc.z + gc.w * wc.w;
        }
        s_cross[t] = (a * invN + imgt_b[t]) * imgt_s[t] + imgt_o[t];
    } else {
        int o = t - 128;
        float pp = 0.f;
        for (int k = 0; k < 4; ++k) pp += s_pt4[k] * invN * pts_w[o * 4 + k];
        s_cross[128 + o] = (pp + pts_b[o]) * pts_s[o] + pts_o[o];
    }
    __syncthreads();
    {
        int br = t >> 7, o = t & 127;
        const float* W = br ? w1i : w1p;
        const float* Wr = W + (size_t)o * 256;
        float hh = 0.f;
        for (int c = 0; c < 256; c += 4) {
            float4 cc = *(const float4*)(s_cross + c);
            float4 wc = *(const float4*)(Wr + c);
            hh += cc.x * wc.x + cc.y * wc.y + cc.z * wc.z + cc.w * wc.w;
        }
        s_h[t] = fmaxf(hh, 0.f);
    }
    __syncthreads();
    {
        int br = t >> 7, o = t & 127;
        const float* W2 = br ? w2i : w2p;
        const float* Wr = W2 + (size_t)o * 128;
        const float* hb = s_h + br * 128;
        float gg = 0.f;
        for (int c = 0; c < 128; c += 4) {
            float4 hc = *(const float4*)(hb + c);
            float4 wc = *(const float4*)(Wr + c);
            gg += hc.x * wc.x + hc.y * wc.y + hc.z * wc.z + hc.w * wc.w;
        }
        ws[F_GATES + br * 128 + o] = 1.f + sigm(gg);
    }
}

// ---------------- K5: MFMA img transform + fully fused epilogue --------------
__global__ __launch_bounds__(256) void k_gemmfuse(
    float* __restrict__ ws, const float* __restrict__ points,
    const float* __restrict__ imgt_b, const float* __restrict__ imgt_s,
    const float* __restrict__ imgt_o,
    const float* __restrict__ pts_w, const float* __restrict__ pts_b,
    const float* __restrict__ pts_s, const float* __restrict__ pts_o,
    float* __restrict__ dout)
{
    __shared__ __hip_bfloat16 s_a[8][4][64][8];
    const ushort* wbf = (const ushort*)(ws + F_IMGTBF);
    int t = threadIdx.x;
    int wid = t >> 6, lane = t & 63, xl = lane & 15, g = lane >> 4;
    int n0 = blockIdx.x * 64;

    {
        int nl = t >> 2, kq = t & 3;
        const uint4* src = (const uint4*)((const ushort*)dout + (size_t)(n0 + nl) * 256) + kq * 8;
#pragma unroll
        for (int kk = 0; kk < 8; ++kk) {
            uint4 v = src[kk];
            int k = kq * 8 + kk;
            *(uint4*)&s_a[k >> 2][k & 3][nl][0] = v;
        }
    }
    __syncthreads();

    f32x4 acc[8];
#pragma unroll
    for (int ni = 0; ni < 8; ++ni) acc[ni] = (f32x4){0.f, 0.f, 0.f, 0.f};

    for (int chunk = 0; chunk < 8; ++chunk) {
        bf16x8 af = *(const bf16x8*)&s_a[chunk][g][wid * 16 + xl][0];
#pragma unroll
        for (int ni = 0; ni < 8; ++ni) {
            bf16x8 bfr = *(const bf16x8*)(wbf + (size_t)(ni * 16 + xl) * 256 + chunk * 32 + g * 8);
            acc[ni] = __builtin_amdgcn_mfma_f32_16x16x32_bf16(af, bfr, acc[ni], 0, 0, 0);
        }
    }

    float4 Pt[4];
#pragma unroll
    for (int j = 0; j < 4; ++j) {
        int np = n0 + wid * 16 + g * 4 + j;
        Pt[j] = *(const float4*)(points + (size_t)np * 5 + 1);
    }
#pragma unroll
    for (int ni = 0; ni < 8; ++ni) {
        int o = ni * 16 + xl;
        float ib = imgt_b[o], isc = imgt_s[o], io = imgt_o[o];
        float gp = ws[F_GATES + o], gi = ws[F_GATES + 128 + o];
        float4 pwv = *(const float4*)(pts_w + o * 4);
        float pb = pts_b[o], psc = pts_s[o], po = pts_o[o];
#pragma unroll
        for (int j = 0; j < 4; ++j) {
            int np = n0 + wid * 16 + g * 4 + j;
            float img = (acc[ni][j] + ib) * isc + io;
            float4 pt = Pt[j];
            float pp = (pt.x * pwv.x + pt.y * pwv.y + pt.z * pwv.z + pt.w * pwv.w + pb) * psc + po;
            dout[(size_t)np * 128 + o] = fmaxf(img * gp + pp * gi, 0.f);
        }
    }
}

// ---------------- launch ------------------------------------------------------
extern "C" void kernel_launch(void* const* d_in, const int* in_sizes, int n_in,
                              void* d_out, int out_size, void* d_ws, size_t ws_size,
                              hipStream_t stream)
{
    const float* fpn0 = (const float*)d_in[0];
    const float* fpn1 = (const float*)d_in[1];
    const float* fpn2 = (const float*)d_in[2];
    const float* fpn3 = (const float*)d_in[3];
    const float* points = (const float*)d_in[4];
    const float* calib  = (const float*)d_in[5];
    const float* lat_w  = (const float*)d_in[6];
    const float* lat_b  = (const float*)d_in[7];
    const float* lat_s  = (const float*)d_in[8];
    const float* lat_o  = (const float*)d_in[9];
    const float* pts_w  = (const float*)d_in[10];
    const float* pts_b  = (const float*)d_in[11];
    const float* pts_s  = (const float*)d_in[12];
    const float* pts_o  = (const float*)d_in[13];
    const float* imgt_w = (const float*)d_in[14];
    const float* imgt_b = (const float*)d_in[15];
    const float* imgt_s = (const float*)d_in[16];
    const float* imgt_o = (const float*)d_in[17];
    const float* la_w1  = (const float*)d_in[18];
    const float* la_b1  = (const float*)d_in[19];
    const float* la_w2  = (const float*)d_in[20];
    const float* la_b2  = (const float*)d_in[21];
    const float* se_pt_w1  = (const float*)d_in[22];
    const float* se_pt_w2  = (const float*)d_in[23];
    const float* se_img_w1 = (const float*)d_in[24];
    const float* se_img_w2 = (const float*)d_in[25];

    float* ws = (float*)d_ws;
    float* dout = (float*)d_out;

    k_prep<<<3138, 256, 0, stream>>>(lat_w, imgt_w, points,
                                     fpn0, fpn1, fpn2, fpn3, ws);
    k_conv_mfma<<<166, 512, 0, stream>>>(ws, lat_b, lat_s, lat_o);
    k_lw<<<1, 64, 0, stream>>>(ws, la_w1, la_b1, la_w2, la_b2);
    k_gather3<<<2048, 256, 0, stream>>>(ws, points, calib, dout);
    k_se<<<1, 256, 0, stream>>>(ws, imgt_w, imgt_b, imgt_s, imgt_o,
                                pts_w, pts_b, pts_s, pts_o,
                                se_pt_w1, se_pt_w2, se_img_w1, se_img_w2);
    k_gemmfuse<<<512, 256, 0, stream>>>(ws, points, imgt_b, imgt_s, imgt_o,
                                        pts_w, pts_b, pts_s, pts_o, dout);
}